// Round 6
// baseline (614.569 us; speedup 1.0000x reference)
//
#include <hip/hip_runtime.h>
#include <hip/hip_bf16.h>

// B=8, S=128, D=1024, H=4096, TOPK=256 -> k = 32768 per batch over S*H=524288 scores.
#define B_  8
#define S_  128
#define D_  1024
#define H_  4096
#define M_  (B_ * S_)          // 1024
#define NSCORE   (M_ * H_)     // 4,194,304
#define PERBATCH (S_ * H_)     // 524,288
#define TOPK_K   (256 * S_)    // 32,768
#define BAND_CAP 8192
#define MARGIN   6e-3f         // 2*E; bf16 gemm2 score error sigma 3.8e-4, z=8 -> 3e-3 = E

#define AS1 __attribute__((address_space(1)))
#define AS3 __attribute__((address_space(3)))

// ---------------- workspace layout (byte offsets) ----------------
#define G_OFF    0u            // g fp32 [1024,4096] 16MB (band_exact reference)
#define SC_OFF   16777216u     // scores fp32 16MB
#define GHI_OFF  33554432u     // ghi bf16 8MB; later down partials (16MB spans GHI+GLO)
#define GLO_OFF  41943040u     // (free) / down partials tail
#define XHI_OFF  50331648u     // x hi bf16 2MB (also value-path A)
#define XLO_OFF  52428800u     // x lo bf16 2MB
#define W1H_OFF  54525952u     // w1 hi 8MB (dead after gemm1)
#define W1L_OFF  62914560u     // w1 lo 8MB
#define W2B_OFF  54525952u     // w2 bf16 32MB (after gemm1); dead after gemm2
#define WPB_OFF  54525952u     // 8MB (after gemm2)
#define WCB_OFF  62914560u     // 8MB
#define WDB_OFF  71303168u     // 8MB
#define ACT_OFF  79691776u     // 8MB
#define H8_OFF   121634816u    // 8x256 u32 (+pad to 64KB)
#define H16_OFF  121700352u    // 8x65536 u32 (2MB)
#define SEL_OFF  123797504u    // 8x4096 u32 (128KB)
#define CNT_OFF  123928576u    // certN[8],bandN[8],prefix1[8],above1[8],Thi[8],Tlo[8]
#define PART_OFF 123929088u    // 1024 u32
#define BIDX_OFF 123933184u    // 8x8192 u32
#define BVAL_OFF 124195328u    // 8x8192 f32

typedef __attribute__((ext_vector_type(8))) short short8;
typedef __attribute__((ext_vector_type(4))) float f32x4;

__device__ __forceinline__ unsigned tokey(float f) {
    unsigned u = __float_as_uint(f);
    return (u & 0x80000000u) ? ~u : (u | 0x80000000u);
}
__device__ __forceinline__ float keytofloat(unsigned k) {
    unsigned u = (k & 0x80000000u) ? (k & 0x7FFFFFFFu) : ~k;
    return __uint_as_float(u);
}
__device__ __forceinline__ unsigned short bfbits(float f) {
    __hip_bfloat16 h = __float2bfloat16(f);
    return *(unsigned short*)&h;
}

// ---------------- fp32 -> (hi, lo) bf16 split ----------------
__global__ __launch_bounds__(256) void split_kernel(const float* __restrict__ in,
                                                    unsigned short* __restrict__ hi,
                                                    unsigned short* __restrict__ lo, int n4) {
    int i = blockIdx.x * 256 + threadIdx.x;
    if (i >= n4) return;
    float4 v = *(const float4*)(in + (size_t)i * 4);
    unsigned short h0 = bfbits(v.x), h1 = bfbits(v.y), h2 = bfbits(v.z), h3 = bfbits(v.w);
    ushort4 hv = {h0, h1, h2, h3};
    float r0 = v.x - __bfloat162float(*(__hip_bfloat16*)&h0);
    float r1 = v.y - __bfloat162float(*(__hip_bfloat16*)&h1);
    float r2 = v.z - __bfloat162float(*(__hip_bfloat16*)&h2);
    float r3 = v.w - __bfloat162float(*(__hip_bfloat16*)&h3);
    ushort4 lv = {bfbits(r0), bfbits(r1), bfbits(r2), bfbits(r3)};
    *(ushort4*)(hi + (size_t)i*4) = hv;
    *(ushort4*)(lo + (size_t)i*4) = lv;
}

// ---------------- fp32 -> bf16 (single) ----------------
__global__ __launch_bounds__(256) void f2bf_kernel(const float* __restrict__ in,
                                                   unsigned short* __restrict__ out, int n4) {
    int i = blockIdx.x * 256 + threadIdx.x;
    if (i >= n4) return;
    float4 v = *(const float4*)(in + (size_t)i * 4);
    ushort4 o = {bfbits(v.x), bfbits(v.y), bfbits(v.z), bfbits(v.w)};
    *(ushort4*)(out + (size_t)i * 4) = o;
}

// ---------------- three fp32 -> bf16 conversions in one launch ----------------
__global__ __launch_bounds__(256) void f2bf3_kernel(const float* __restrict__ s0,
                                                    const float* __restrict__ s1,
                                                    const float* __restrict__ s2,
                                                    unsigned short* __restrict__ d0,
                                                    unsigned short* __restrict__ d1,
                                                    unsigned short* __restrict__ d2) {
    const int Q = H_ * D_ / 4;
    int i = blockIdx.x * 256 + threadIdx.x;
    int w = i / Q, j = i - w * Q;
    const float* s = (w == 0) ? s0 : (w == 1) ? s1 : s2;
    unsigned short* d = (w == 0) ? d0 : (w == 1) ? d1 : d2;
    float4 v = *(const float4*)(s + (size_t)j * 4);
    ushort4 o = {bfbits(v.x), bfbits(v.y), bfbits(v.z), bfbits(v.w)};
    *(ushort4*)(d + (size_t)j * 4) = o;
}

// ---------------- gemm1: split-bf16 3-term, 64x128 tile, BK=64, swizzled LDS ----------------
// g = relu(x.w1^T + b1) fp32; ghi = bf16(g). K = 1024. Grid (32, 16).
__global__ __launch_bounds__(256) void gemm1_kernel(const short* __restrict__ Ahg,
                                                    const short* __restrict__ Alg,
                                                    const short* __restrict__ Bhg,
                                                    const short* __restrict__ Blg,
                                                    const float* __restrict__ bias,
                                                    float* __restrict__ C,
                                                    unsigned short* __restrict__ hi) {
    __shared__ short lAh[64*64], lAl[64*64], lBh[128*64], lBl[128*64];   // 48 KB
    const int tid = threadIdx.x, lane = tid & 63, wave = tid >> 6;
    const int row0 = blockIdx.y * 64, col0 = blockIdx.x * 128;
    f32x4 acc[4][2] = {};
    for (int kt = 0; kt < D_; kt += 64) {
        #pragma unroll
        for (int q = 0; q < 2; q++) {
            int l = q * 256 + tid;
            int r = l >> 3, cg = ((l & 7) ^ (r & 7)) * 8;
            size_t go = (size_t)(row0 + r) * D_ + kt + cg;
            __builtin_amdgcn_global_load_lds((const AS1 unsigned*)(Ahg + go),
                (AS3 unsigned*)(lAh + l * 8), 16, 0, 0);
            __builtin_amdgcn_global_load_lds((const AS1 unsigned*)(Alg + go),
                (AS3 unsigned*)(lAl + l * 8), 16, 0, 0);
        }
        #pragma unroll
        for (int q = 0; q < 4; q++) {
            int l = q * 256 + tid;
            int r = l >> 3, cg = ((l & 7) ^ (r & 7)) * 8;
            size_t go = (size_t)(col0 + r) * D_ + kt + cg;
            __builtin_amdgcn_global_load_lds((const AS1 unsigned*)(Bhg + go),
                (AS3 unsigned*)(lBh + l * 8), 16, 0, 0);
            __builtin_amdgcn_global_load_lds((const AS1 unsigned*)(Blg + go),
                (AS3 unsigned*)(lBl + l * 8), 16, 0, 0);
        }
        __syncthreads();
        #pragma unroll
        for (int kk = 0; kk < 2; kk++) {
            const int cb = kk * 4 + (lane >> 4);
            short8 ah[4], al[4], bh[2], bl[2];
            #pragma unroll
            for (int i = 0; i < 4; i++) {
                int r = i * 16 + (lane & 15);
                int s = (r * 8 + (cb ^ (r & 7))) * 8;
                ah[i] = *(const short8*)(lAh + s);
                al[i] = *(const short8*)(lAl + s);
            }
            #pragma unroll
            for (int j = 0; j < 2; j++) {
                int r = wave * 32 + j * 16 + (lane & 15);
                int s = (r * 8 + (cb ^ (r & 7))) * 8;
                bh[j] = *(const short8*)(lBh + s);
                bl[j] = *(const short8*)(lBl + s);
            }
            #pragma unroll
            for (int i = 0; i < 4; i++)
                #pragma unroll
                for (int j = 0; j < 2; j++) {
                    acc[i][j] = __builtin_amdgcn_mfma_f32_16x16x32_bf16(al[i], bh[j], acc[i][j], 0, 0, 0);
                    acc[i][j] = __builtin_amdgcn_mfma_f32_16x16x32_bf16(ah[i], bl[j], acc[i][j], 0, 0, 0);
                    acc[i][j] = __builtin_amdgcn_mfma_f32_16x16x32_bf16(ah[i], bh[j], acc[i][j], 0, 0, 0);
                }
        }
        __syncthreads();
    }
    #pragma unroll
    for (int i = 0; i < 4; i++) {
        int row = row0 + i * 16 + (lane >> 4) * 4;
        #pragma unroll
        for (int j = 0; j < 2; j++) {
            int col = col0 + wave * 32 + j * 16 + (lane & 15);
            float bv = bias[col];
            #pragma unroll
            for (int r = 0; r < 4; r++) {
                float v = fmaxf(acc[i][j][r] + bv, 0.0f);
                size_t o = (size_t)(row + r) * H_ + col;
                C[o] = v;
                hi[o] = bfbits(v);
            }
        }
    }
}

// ---------------- gemm2: plain bf16, 64x128 tile, BK=64, swizzled; fused hist8 ----------------
// scores = ghi.w2b^T + b2. K = 4096. Grid (32, 16).
__global__ __launch_bounds__(256) void gemm2_kernel(const short* __restrict__ Ahg,
                                                    const short* __restrict__ Bhg,
                                                    const float* __restrict__ bias,
                                                    float* __restrict__ C,
                                                    unsigned* __restrict__ h8) {
    __shared__ short lAh[64*64], lBh[128*64];   // 24 KB
    __shared__ unsigned lh[256];
    const int tid = threadIdx.x, lane = tid & 63, wave = tid >> 6;
    const int row0 = blockIdx.y * 64, col0 = blockIdx.x * 128;
    lh[tid] = 0;
    f32x4 acc[4][2] = {};
    for (int kt = 0; kt < H_; kt += 64) {
        #pragma unroll
        for (int q = 0; q < 2; q++) {
            int l = q * 256 + tid;
            int r = l >> 3, cg = ((l & 7) ^ (r & 7)) * 8;
            __builtin_amdgcn_global_load_lds(
                (const AS1 unsigned*)(Ahg + (size_t)(row0 + r) * H_ + kt + cg),
                (AS3 unsigned*)(lAh + l * 8), 16, 0, 0);
        }
        #pragma unroll
        for (int q = 0; q < 4; q++) {
            int l = q * 256 + tid;
            int r = l >> 3, cg = ((l & 7) ^ (r & 7)) * 8;
            __builtin_amdgcn_global_load_lds(
                (const AS1 unsigned*)(Bhg + (size_t)(col0 + r) * H_ + kt + cg),
                (AS3 unsigned*)(lBh + l * 8), 16, 0, 0);
        }
        __syncthreads();
        #pragma unroll
        for (int kk = 0; kk < 2; kk++) {
            const int cb = kk * 4 + (lane >> 4);
            short8 ah[4], bh[2];
            #pragma unroll
            for (int i = 0; i < 4; i++) {
                int r = i * 16 + (lane & 15);
                ah[i] = *(const short8*)(lAh + (r * 8 + (cb ^ (r & 7))) * 8);
            }
            #pragma unroll
            for (int j = 0; j < 2; j++) {
                int r = wave * 32 + j * 16 + (lane & 15);
                bh[j] = *(const short8*)(lBh + (r * 8 + (cb ^ (r & 7))) * 8);
            }
            #pragma unroll
            for (int i = 0; i < 4; i++)
                #pragma unroll
                for (int j = 0; j < 2; j++)
                    acc[i][j] = __builtin_amdgcn_mfma_f32_16x16x32_bf16(ah[i], bh[j], acc[i][j], 0, 0, 0);
        }
        __syncthreads();
    }
    const int b = row0 >> 7;
    #pragma unroll
    for (int i = 0; i < 4; i++) {
        int row = row0 + i * 16 + (lane >> 4) * 4;
        #pragma unroll
        for (int j = 0; j < 2; j++) {
            int col = col0 + wave * 32 + j * 16 + (lane & 15);
            float bv = bias[col];
            #pragma unroll
            for (int r = 0; r < 4; r++) {
                float v = acc[i][j][r] + bv;
                C[(size_t)(row + r) * H_ + col] = v;
                atomicAdd(&lh[tokey(v) >> 24], 1u);
            }
        }
    }
    __syncthreads();
    unsigned hv = lh[tid];
    if (hv) atomicAdd(&h8[(b << 8) + tid], hv);
}

// ---------------- fused up-proj: B-rows gathered by sel, bias-select + GELU epilogue --------
// act = gelu(x . (sel? wprev : wcurr)^T + (sel? bp : bc)). Grid (32, 8): batch = blockIdx.y.
__global__ __launch_bounds__(256) void upgemm_kernel(const short* __restrict__ A,
                                                     const short* __restrict__ Wp,
                                                     const short* __restrict__ Wc,
                                                     const float* __restrict__ bp,
                                                     const float* __restrict__ bc,
                                                     const unsigned* __restrict__ sel,
                                                     __hip_bfloat16* __restrict__ act) {
    __shared__ short As[128 * 32];
    __shared__ short Bs[128 * 32];
    const int tid = threadIdx.x, lane = tid & 63, wave = tid >> 6;
    const int wr = wave >> 1, wcol = wave & 1;
    const int b = blockIdx.y;
    const int row0 = b * 128, col0 = blockIdx.x * 128;
    const int r_ld = tid >> 2, c_ld = (tid & 3) * 8;
    const short* B0 = sel[(b << 12) + col0 + r_ld]      ? Wp : Wc;
    const short* B1 = sel[(b << 12) + col0 + 64 + r_ld] ? Wp : Wc;
    f32x4 acc[4][4] = {};
    for (int kt = 0; kt < D_; kt += 32) {
        __builtin_amdgcn_global_load_lds(
            (const AS1 unsigned*)(A + (size_t)(row0 + r_ld) * D_ + kt + c_ld),
            (AS3 unsigned*)(As + r_ld * 32 + c_ld), 16, 0, 0);
        __builtin_amdgcn_global_load_lds(
            (const AS1 unsigned*)(A + (size_t)(row0 + 64 + r_ld) * D_ + kt + c_ld),
            (AS3 unsigned*)(As + (64 + r_ld) * 32 + c_ld), 16, 0, 0);
        __builtin_amdgcn_global_load_lds(
            (const AS1 unsigned*)(B0 + (size_t)(col0 + r_ld) * D_ + kt + c_ld),
            (AS3 unsigned*)(Bs + r_ld * 32 + c_ld), 16, 0, 0);
        __builtin_amdgcn_global_load_lds(
            (const AS1 unsigned*)(B1 + (size_t)(col0 + 64 + r_ld) * D_ + kt + c_ld),
            (AS3 unsigned*)(Bs + (64 + r_ld) * 32 + c_ld), 16, 0, 0);
        __syncthreads();
        short8 af[4], bfr[4];
        #pragma unroll
        for (int t = 0; t < 4; t++) {
            af[t]  = *(const short8*)(As + (wr*64 + t*16 + (lane & 15)) * 32 + (lane >> 4) * 8);
            bfr[t] = *(const short8*)(Bs + (wcol*64 + t*16 + (lane & 15)) * 32 + (lane >> 4) * 8);
        }
        #pragma unroll
        for (int tm = 0; tm < 4; tm++)
            #pragma unroll
            for (int tn = 0; tn < 4; tn++)
                acc[tm][tn] = __builtin_amdgcn_mfma_f32_16x16x32_bf16(af[tm], bfr[tn], acc[tm][tn], 0, 0, 0);
        __syncthreads();
    }
    #pragma unroll
    for (int tm = 0; tm < 4; tm++) {
        int row = row0 + wr*64 + tm*16 + (lane >> 4) * 4;
        #pragma unroll
        for (int tn = 0; tn < 4; tn++) {
            int col = col0 + wcol*64 + tn*16 + (lane & 15);
            float bv = sel[(b << 12) + col] ? bp[col] : bc[col];
            #pragma unroll
            for (int r = 0; r < 4; r++) {
                float v = acc[tm][tn][r] + bv;
                float gl = 0.5f * v * (1.0f + erff(v * 0.70710678118654752440f));
                act[(size_t)(row + r) * H_ + col] = __float2bfloat16(gl);
            }
        }
    }
}

// ---------------- down-proj with split-K=4 into partial buffers ----------------
__global__ __launch_bounds__(256) void bgemm_down_kernel(const short* __restrict__ A,
                                                         const short* __restrict__ Bw,
                                                         float* __restrict__ P) {
    __shared__ short As[128 * 32];
    __shared__ short Bs[128 * 32];
    const int tid = threadIdx.x, lane = tid & 63, wave = tid >> 6;
    const int wr = wave >> 1, wc = wave & 1;
    const int row0 = blockIdx.y * 128, col0 = blockIdx.x * 128;
    const int k0 = blockIdx.z * (H_ / 4);
    float* C = P + (size_t)blockIdx.z * (M_ * D_);
    const int r_ld = tid >> 2, c_ld = (tid & 3) * 8;
    f32x4 acc[4][4] = {};
    for (int kt = k0; kt < k0 + H_ / 4; kt += 32) {
        #pragma unroll
        for (int half = 0; half < 2; half++) {
            int r = half * 64 + r_ld;
            __builtin_amdgcn_global_load_lds(
                (const AS1 unsigned*)(A + (size_t)(row0 + r) * H_ + kt + c_ld),
                (AS3 unsigned*)(As + r * 32 + c_ld), 16, 0, 0);
            __builtin_amdgcn_global_load_lds(
                (const AS1 unsigned*)(Bw + (size_t)(col0 + r) * H_ + kt + c_ld),
                (AS3 unsigned*)(Bs + r * 32 + c_ld), 16, 0, 0);
        }
        __syncthreads();
        short8 af[4], bfr[4];
        #pragma unroll
        for (int t = 0; t < 4; t++) {
            af[t]  = *(const short8*)(As + (wr*64 + t*16 + (lane & 15)) * 32 + (lane >> 4) * 8);
            bfr[t] = *(const short8*)(Bs + (wc*64 + t*16 + (lane & 15)) * 32 + (lane >> 4) * 8);
        }
        #pragma unroll
        for (int tm = 0; tm < 4; tm++)
            #pragma unroll
            for (int tn = 0; tn < 4; tn++)
                acc[tm][tn] = __builtin_amdgcn_mfma_f32_16x16x32_bf16(af[tm], bfr[tn], acc[tm][tn], 0, 0, 0);
        __syncthreads();
    }
    #pragma unroll
    for (int tm = 0; tm < 4; tm++) {
        int row = row0 + wr*64 + tm*16 + (lane >> 4) * 4;
        #pragma unroll
        for (int tn = 0; tn < 4; tn++) {
            int col = col0 + wc*64 + tn*16 + (lane & 15);
            #pragma unroll
            for (int r = 0; r < 4; r++)
                C[(size_t)(row + r) * D_ + col] = acc[tm][tn][r];
        }
    }
}

__global__ __launch_bounds__(256) void down_merge_kernel(const float* __restrict__ P,
                                                         const float* __restrict__ db,
                                                         float* __restrict__ out) {
    int i = blockIdx.x * 256 + threadIdx.x;
    if (i >= M_ * D_ / 4) return;
    int col = (i * 4) & (D_ - 1);
    float4 a = *(const float4*)(P + (size_t)i * 4);
    float4 b = *(const float4*)(P + (size_t)(M_*D_) + (size_t)i * 4);
    float4 c = *(const float4*)(P + (size_t)(2*M_*D_) + (size_t)i * 4);
    float4 d = *(const float4*)(P + (size_t)(3*M_*D_) + (size_t)i * 4);
    float4 o;
    o.x = a.x + b.x + c.x + d.x + db[col+0];
    o.y = a.y + b.y + c.y + d.y + db[col+1];
    o.z = a.z + b.z + c.z + d.z + db[col+2];
    o.w = a.w + b.w + c.w + d.w + db[col+3];
    *(float4*)(out + (size_t)i * 4) = o;
}

// ---------------- threshold scans ----------------
__global__ __launch_bounds__(256) void scan8_kernel(const unsigned* __restrict__ h8,
                                                    unsigned* __restrict__ prefix1,
                                                    unsigned* __restrict__ above1) {
    int b = blockIdx.x, tid = threadIdx.x;
    __shared__ unsigned S[256];
    __shared__ int tstar;
    S[tid] = h8[(b << 8) + tid];
    __syncthreads();
    for (int off = 1; off < 256; off <<= 1) {
        unsigned a = S[tid];
        unsigned v = (tid + off < 256) ? S[tid + off] : 0u;
        __syncthreads();
        S[tid] = a + v;
        __syncthreads();
    }
    unsigned St = S[tid];
    unsigned Sn = (tid < 255) ? S[tid + 1] : 0u;
    if (St >= TOPK_K && (tid == 255 || Sn < TOPK_K)) tstar = tid;
    __syncthreads();
    if (tid == 0) {
        prefix1[b] = (unsigned)tstar;
        above1[b]  = (tstar < 255) ? S[tstar + 1] : 0u;
    }
}

__global__ __launch_bounds__(256) void hist16_kernel(const float* __restrict__ scores,
                                                     const unsigned* __restrict__ prefix1,
                                                     unsigned* __restrict__ h16) {
    int i = blockIdx.x * 256 + threadIdx.x;
    if (i >= NSCORE) return;
    int b = i >> 19;
    unsigned key = tokey(scores[i]);
    if ((key >> 24) == prefix1[b])
        atomicAdd(&h16[((size_t)b << 16) + ((key >> 8) & 0xFFFFu)], 1u);
}

__global__ __launch_bounds__(256) void scan16_kernel(const unsigned* __restrict__ h16,
                                                     const unsigned* __restrict__ prefix1,
                                                     const unsigned* __restrict__ above1,
                                                     float* __restrict__ Thi,
                                                     float* __restrict__ Tlo) {
    int b = blockIdx.x, tid = threadIdx.x;
    const unsigned* h = h16 + ((size_t)b << 16);
    unsigned k = TOPK_K - above1[b];
    __shared__ unsigned S[256];
    __shared__ int tstar;
    unsigned s = 0;
    const unsigned* seg = h + tid * 256;
    for (int i = 0; i < 256; i++) s += seg[i];
    S[tid] = s;
    __syncthreads();
    for (int off = 1; off < 256; off <<= 1) {
        unsigned a = S[tid];
        unsigned v = (tid + off < 256) ? S[tid + off] : 0u;
        __syncthreads();
        S[tid] = a + v;
        __syncthreads();
    }
    unsigned St = S[tid];
    unsigned Sn = (tid < 255) ? S[tid + 1] : 0u;
    if (St >= k && (tid == 255 || Sn < k)) tstar = tid;
    __syncthreads();
    if (tid == 0) {
        int t = tstar;
        unsigned runn = (t < 255) ? S[t + 1] : 0u;
        unsigned c = (unsigned)t * 256u;
        for (int i = 255; i >= 0; i--) {
            unsigned cc = h[t * 256 + i];
            if (runn + cc >= k) { c = (unsigned)(t * 256 + i); break; }
            runn += cc;
        }
        unsigned P24 = (prefix1[b] << 16) | c;
        float tlo = (P24 < 0x8000u) ? -INFINITY : keytofloat(P24 << 8);
        float thi = (P24 == 0x00FFFFFFu) ? INFINITY
                  : ((P24 + 1u) < 0x8000u ? -INFINITY : keytofloat((P24 + 1u) << 8));
        Thi[b] = thi + MARGIN;
        Tlo[b] = tlo - MARGIN;
    }
}

// ---------------- classify: block-owned tiles; LDS-buffered band append ----------------
__global__ __launch_bounds__(256) void classify_kernel(const float* __restrict__ scores,
                                                       const float* __restrict__ Thi,
                                                       const float* __restrict__ Tlo,
                                                       unsigned* __restrict__ sel,
                                                       unsigned* __restrict__ partialCnt,
                                                       unsigned* __restrict__ bandN,
                                                       unsigned* __restrict__ bandIdx) {
    const int b  = blockIdx.z;
    const int h0 = blockIdx.x * 256;
    const int s0 = blockIdx.y * 16;
    const int c  = threadIdx.x;
    const float thi = Thi[b], tlo = Tlo[b];
    __shared__ unsigned lidx[1024];
    __shared__ unsigned lcnt, lbase;
    __shared__ unsigned red[256];
    if (c == 0) lcnt = 0;
    __syncthreads();
    unsigned selbit = 0, cnt = 0;
    const float* base = scores + ((size_t)(b * S_ + s0)) * H_ + h0;
    #pragma unroll 4
    for (int j = 0; j < 16; j++) {
        float sv = base[(size_t)j * H_ + c];
        if (sv > thi) { selbit = 1u; cnt++; }
        else if (sv >= tlo) {
            unsigned slot = atomicAdd(&lcnt, 1u);        // LDS atomic — fast
            if (slot < 1024u) lidx[slot] = (unsigned)(((s0 + j) << 12) | (h0 + c));
        }
    }
    if (selbit) sel[(b << 12) + h0 + c] = 1u;
    red[c] = cnt;
    __syncthreads();
    for (int off = 128; off; off >>= 1) {
        if (c < off) red[c] += red[c + off];
        __syncthreads();
    }
    unsigned nloc = lcnt > 1024u ? 1024u : lcnt;
    if (c == 0) {
        partialCnt[b * 128 + blockIdx.y * 16 + blockIdx.x] = red[0];
        lbase = nloc ? atomicAdd(&bandN[b], nloc) : 0u;  // one global atomic per block
    }
    __syncthreads();
    for (unsigned i = c; i < nloc; i += 256) {
        unsigned p = lbase + i;
        if (p < BAND_CAP) bandIdx[(b << 13) + p] = lidx[i];
    }
}

__global__ void finalize_cnt_kernel(const unsigned* __restrict__ partial,
                                    unsigned* __restrict__ certN) {
    int b = threadIdx.x;
    if (b >= B_) return;
    unsigned s = 0;
    for (int i = 0; i < 128; i++) s += partial[b * 128 + i];
    certN[b] = s;
}

// ---------------- exact fp32 score for band entries (one wave each) ----------------
__global__ __launch_bounds__(256) void band_exact_kernel(const float* __restrict__ g,
                                                         const float* __restrict__ w2,
                                                         const float* __restrict__ b2,
                                                         const unsigned* __restrict__ bandN,
                                                         const unsigned* __restrict__ bandIdx,
                                                         float* __restrict__ bandVal) {
    int wid = (blockIdx.x * 256 + threadIdx.x) >> 6;
    int lane = threadIdx.x & 63;
    for (int b = 0; b < B_; b++) {
        int n = bandN[b]; if (n > BAND_CAP) n = BAND_CAP;
        for (int j = wid; j < n; j += 1024) {
            unsigned f = bandIdx[(b << 13) + j];
            int m = b * S_ + (int)(f >> 12);
            int h = (int)(f & (H_ - 1));
            const float* gr = g  + (size_t)m * H_;
            const float* wr = w2 + (size_t)h * H_;
            float s = 0.0f;
            for (int cc = lane * 4; cc < H_; cc += 256) {
                float4 a = *(const float4*)(gr + cc);
                float4 w = *(const float4*)(wr + cc);
                s += a.x*w.x + a.y*w.y + a.z*w.z + a.w*w.w;
            }
            #pragma unroll
            for (int off = 32; off; off >>= 1) s += __shfl_xor(s, off);
            if (lane == 0) bandVal[(b << 13) + j] = s + b2[h];
        }
    }
}

// ---------------- band top-r via LDS histogram (O(n)) ----------------
#define NBIN 4096
__global__ __launch_bounds__(256) void band_select_kernel(const float* __restrict__ bandVal,
                                                          const unsigned* __restrict__ bandIdx,
                                                          const unsigned* __restrict__ bandN,
                                                          const unsigned* __restrict__ certN,
                                                          const float* __restrict__ ThiA,
                                                          const float* __restrict__ TloA,
                                                          unsigned* __restrict__ sel) {
    int b = blockIdx.x, tid = threadIdx.x;
    int n = bandN[b]; if (n > BAND_CAP) n = BAND_CAP;
    int r = TOPK_K - (int)certN[b];
    if (r <= 0) return;
    if (r >= n) {
        for (int j = tid; j < n; j += 256)
            sel[(b << 12) + (bandIdx[(b << 13) + j] & (H_ - 1))] = 1u;
        return;
    }
    const float lo = TloA[b];
    const float scale = (float)NBIN / (ThiA[b] - lo);
    __shared__ unsigned hist[NBIN];
    __shared__ unsigned part[256];
    __shared__ unsigned bstar, cabove, mcnt;
    for (int i = tid; i < NBIN; i += 256) hist[i] = 0;
    if (tid == 0) mcnt = 0;
    __syncthreads();
    for (int j = tid; j < n; j += 256) {
        float v = bandVal[(b << 13) + j];
        int bin = (int)((v - lo) * scale);
        bin = bin < 0 ? 0 : (bin >= NBIN ? NBIN - 1 : bin);
        atomicAdd(&hist[bin], 1u);
    }
    __syncthreads();
    unsigned s = 0;
    for (int i = 0; i < 16; i++) s += hist[tid * 16 + i];
    part[tid] = s;
    __syncthreads();
    for (int off = 1; off < 256; off <<= 1) {
        unsigned a = part[tid];
        unsigned v = (tid + off < 256) ? part[tid + off] : 0u;
        __syncthreads();
        part[tid] = a + v;
        __syncthreads();
    }
    unsigned St = part[tid], Sn = (tid < 255) ? part[tid + 1] : 0u;
    if (St >= (unsigned)r && (tid == 255 || Sn < (unsigned)r)) {
        unsigned runn = Sn;
        for (int i = 15; i >= 0; i--) {
            unsigned c = hist[tid * 16 + i];
            if (runn + c >= (unsigned)r) { bstar = (unsigned)(tid * 16 + i); cabove = runn; break; }
            runn += c;
        }
    }
    __syncthreads();
    const int bs = (int)bstar;
    __shared__ float  cv[512];
    __shared__ unsigned ci[512];
    for (int j = tid; j < n; j += 256) {
        float v = bandVal[(b << 13) + j];
        unsigned f = bandIdx[(b << 13) + j];
        int bin = (int)((v - lo) * scale);
        bin = bin < 0 ? 0 : (bin >= NBIN ? NBIN - 1 : bin);
        if (bin > bs) sel[(b << 12) + (f & (H_ - 1))] = 1u;
        else if (bin == bs) {
            unsigned slot = atomicAdd(&mcnt, 1u);
            if (slot < 512u) { cv[slot] = v; ci[slot] = f; }
        }
    }
    __syncthreads();
    int need = r - (int)cabove;
    int mm = mcnt > 512u ? 512 : (int)mcnt;
    for (int j = tid; j < mm; j += 256) {
        float vj = cv[j]; unsigned fj = ci[j];
        int rank = 0;
        for (int l = 0; l < mm; l++) {
            float vl = cv[l]; unsigned fl = ci[l];
            rank += (vl > vj) || (vl == vj && fl < fj);
        }
        if (rank < need) sel[(b << 12) + (fj & (H_ - 1))] = 1u;
    }
}

extern "C" void kernel_launch(void* const* d_in, const int* in_sizes, int n_in,
                              void* d_out, int out_size, void* d_ws, size_t ws_size,
                              hipStream_t stream) {
    const float* x     = (const float*)d_in[0];
    const float* wprev = (const float*)d_in[1];
    const float* bprev = (const float*)d_in[2];
    const float* wcurr = (const float*)d_in[3];
    const float* bcurr = (const float*)d_in[4];
    const float* gw1   = (const float*)d_in[5];
    const float* gb1   = (const float*)d_in[6];
    const float* gw2   = (const float*)d_in[7];
    const float* gb2   = (const float*)d_in[8];
    const float* dw    = (const float*)d_in[9];
    const float* db    = (const float*)d_in[10];
    float* out = (float*)d_out;
    char* ws = (char*)d_ws;

    float* g      = (float*)(ws + G_OFF);
    float* scores = (float*)(ws + SC_OFF);
    float* dpart  = (float*)(ws + GHI_OFF);          // 16MB (GHI+GLO), after ghi dead
    unsigned short* ghi = (unsigned short*)(ws + GHI_OFF);
    unsigned short* xhi = (unsigned short*)(ws + XHI_OFF);
    unsigned short* xlo = (unsigned short*)(ws + XLO_OFF);
    unsigned short* w1h = (unsigned short*)(ws + W1H_OFF);
    unsigned short* w1l = (unsigned short*)(ws + W1L_OFF);
    unsigned short* w2b = (unsigned short*)(ws + W2B_OFF);
    unsigned short* wpb = (unsigned short*)(ws + WPB_OFF);
    unsigned short* wcb = (unsigned short*)(ws + WCB_OFF);
    unsigned short* wdb = (unsigned short*)(ws + WDB_OFF);
    __hip_bfloat16* act = (__hip_bfloat16*)(ws + ACT_OFF);
    unsigned* h8      = (unsigned*)(ws + H8_OFF);
    unsigned* h16     = (unsigned*)(ws + H16_OFF);
    unsigned* sel     = (unsigned*)(ws + SEL_OFF);
    unsigned* certN   = (unsigned*)(ws + CNT_OFF);
    unsigned* bandN   = (unsigned*)(ws + CNT_OFF + 32);
    unsigned* prefix1 = (unsigned*)(ws + CNT_OFF + 64);
    unsigned* above1  = (unsigned*)(ws + CNT_OFF + 96);
    float*    Thi     = (float*)(ws + CNT_OFF + 128);
    float*    Tlo     = (float*)(ws + CNT_OFF + 160);
    unsigned* partCnt = (unsigned*)(ws + PART_OFF);
    unsigned* bandIdx = (unsigned*)(ws + BIDX_OFF);
    float*    bandVal = (float*)(ws + BVAL_OFF);

    hipMemsetAsync(ws + H8_OFF, 0, 65536 + 2097152, stream);      // h8 + pad + h16
    hipMemsetAsync(ws + SEL_OFF, 0, 131072 + 512 + 4096, stream); // sel + counters + partCnt

    // gate path
    split_kernel<<<(M_*D_/4 + 255)/256, 256, 0, stream>>>(x,   xhi, xlo, M_*D_/4);
    split_kernel<<<(H_*D_/4 + 255)/256, 256, 0, stream>>>(gw1, w1h, w1l, H_*D_/4);
    gemm1_kernel<<<dim3(H_/128, M_/64), 256, 0, stream>>>(
        (const short*)xhi, (const short*)xlo, (const short*)w1h, (const short*)w1l,
        gb1, g, ghi);
    f2bf_kernel<<<(H_*H_/4 + 255)/256, 256, 0, stream>>>(gw2, w2b, H_*H_/4);   // overwrites w1
    gemm2_kernel<<<dim3(H_/128, M_/64), 256, 0, stream>>>(
        (const short*)ghi, (const short*)w2b, gb2, scores, h8);

    // value-path bf16 weights (overwrite w2b region -> after gemm2)
    f2bf3_kernel<<<3*(H_*D_/4)/256, 256, 0, stream>>>(wprev, wcurr, dw, wpb, wcb, wdb);

    // threshold + classify + band refine
    scan8_kernel<<<B_, 256, 0, stream>>>(h8, prefix1, above1);
    hist16_kernel<<<NSCORE/256, 256, 0, stream>>>(scores, prefix1, h16);
    scan16_kernel<<<B_, 256, 0, stream>>>(h16, prefix1, above1, Thi, Tlo);
    classify_kernel<<<dim3(16, 8, 8), 256, 0, stream>>>(scores, Thi, Tlo, sel, partCnt, bandN, bandIdx);
    finalize_cnt_kernel<<<1, 64, 0, stream>>>(partCnt, certN);
    band_exact_kernel<<<256, 256, 0, stream>>>(g, gw2, gb2, bandN, bandIdx, bandVal);
    band_select_kernel<<<B_, 256, 0, stream>>>(bandVal, bandIdx, bandN, certN, Thi, Tlo, sel);

    // value path: fused up-proj (sel-gathered weights + bias + GELU), down-proj, merge
    upgemm_kernel<<<dim3(H_/128, B_), 256, 0, stream>>>(
        (const short*)xhi, (const short*)wpb, (const short*)wcb, bprev, bcurr, sel, act);
    bgemm_down_kernel<<<dim3(D_/128, M_/128, 4), 256, 0, stream>>>(
        (const short*)act, (const short*)wdb, dpart);
    down_merge_kernel<<<(M_*D_/4 + 255)/256, 256, 0, stream>>>(dpart, db, out);
}

// Round 7
// 502.995 us; speedup vs baseline: 1.2218x; 1.2218x over previous
//
#include <hip/hip_runtime.h>
#include <hip/hip_bf16.h>

// B=8, S=128, D=1024, H=4096, TOPK=256 -> k = 32768 per batch over S*H=524288 scores.
#define B_  8
#define S_  128
#define D_  1024
#define H_  4096
#define M_  (B_ * S_)          // 1024
#define NSCORE   (M_ * H_)     // 4,194,304
#define PERBATCH (S_ * H_)     // 524,288
#define TOPK_K   (256 * S_)    // 32,768
#define BAND_CAP 8192
#define MARGIN   6e-3f         // 2*E; bf16 gemm2 score error sigma ~4.8e-4, max ~2.6e-3

#define AS1 __attribute__((address_space(1)))
#define AS3 __attribute__((address_space(3)))

// ---------------- workspace layout (byte offsets) ----------------
#define G_OFF    0u            // g fp32 [1024,4096] 16MB (band_exact reference)
#define SC_OFF   16777216u     // scores fp32 16MB
#define GHI_OFF  33554432u     // ghi bf16 8MB; later down partials (16MB spans GHI+GLO)
#define GLO_OFF  41943040u     // (free) / down partials tail
#define XHI_OFF  50331648u     // x hi bf16 2MB (also value-path A)
#define XLO_OFF  52428800u     // x lo bf16 2MB
#define W1H_OFF  54525952u     // w1 hi 8MB (dead after gemm1)
#define W1L_OFF  62914560u     // w1 lo 8MB
#define W2B_OFF  54525952u     // w2 bf16 32MB (after gemm1); dead after gemm2
#define WPB_OFF  54525952u     // 8MB (after gemm2)
#define WCB_OFF  62914560u     // 8MB
#define WDB_OFF  71303168u     // 8MB
#define ACT_OFF  79691776u     // 8MB
#define H8_OFF   121634816u    // 8x256 u32 (+pad to 64KB)
#define H16_OFF  121700352u    // 8x65536 u32 (2MB)
#define SEL_OFF  123797504u    // 8x4096 u32 (128KB)
#define CNT_OFF  123928576u    // certN[8],bandN[8],prefix1[8],above1[8],Thi[8],Tlo[8]
#define PART_OFF 123929088u    // 1024 u32
#define BIDX_OFF 123933184u    // 8x8192 u32
#define BVAL_OFF 124195328u    // 8x8192 f32

typedef __attribute__((ext_vector_type(8))) short short8;
typedef __attribute__((ext_vector_type(4))) float f32x4;

__device__ __forceinline__ unsigned tokey(float f) {
    unsigned u = __float_as_uint(f);
    return (u & 0x80000000u) ? ~u : (u | 0x80000000u);
}
__device__ __forceinline__ float keytofloat(unsigned k) {
    unsigned u = (k & 0x80000000u) ? (k & 0x7FFFFFFFu) : ~k;
    return __uint_as_float(u);
}
__device__ __forceinline__ unsigned short bfbits(float f) {
    __hip_bfloat16 h = __float2bfloat16(f);
    return *(unsigned short*)&h;
}

// ---------------- fp32 -> (hi, lo) bf16 split ----------------
__global__ __launch_bounds__(256) void split_kernel(const float* __restrict__ in,
                                                    unsigned short* __restrict__ hi,
                                                    unsigned short* __restrict__ lo, int n4) {
    int i = blockIdx.x * 256 + threadIdx.x;
    if (i >= n4) return;
    float4 v = *(const float4*)(in + (size_t)i * 4);
    unsigned short h0 = bfbits(v.x), h1 = bfbits(v.y), h2 = bfbits(v.z), h3 = bfbits(v.w);
    ushort4 hv = {h0, h1, h2, h3};
    float r0 = v.x - __bfloat162float(*(__hip_bfloat16*)&h0);
    float r1 = v.y - __bfloat162float(*(__hip_bfloat16*)&h1);
    float r2 = v.z - __bfloat162float(*(__hip_bfloat16*)&h2);
    float r3 = v.w - __bfloat162float(*(__hip_bfloat16*)&h3);
    ushort4 lv = {bfbits(r0), bfbits(r1), bfbits(r2), bfbits(r3)};
    *(ushort4*)(hi + (size_t)i*4) = hv;
    *(ushort4*)(lo + (size_t)i*4) = lv;
}

// ---------------- fp32 -> bf16 (single) ----------------
__global__ __launch_bounds__(256) void f2bf_kernel(const float* __restrict__ in,
                                                   unsigned short* __restrict__ out, int n4) {
    int i = blockIdx.x * 256 + threadIdx.x;
    if (i >= n4) return;
    float4 v = *(const float4*)(in + (size_t)i * 4);
    ushort4 o = {bfbits(v.x), bfbits(v.y), bfbits(v.z), bfbits(v.w)};
    *(ushort4*)(out + (size_t)i * 4) = o;
}

// ---------------- three fp32 -> bf16 conversions in one launch ----------------
__global__ __launch_bounds__(256) void f2bf3_kernel(const float* __restrict__ s0,
                                                    const float* __restrict__ s1,
                                                    const float* __restrict__ s2,
                                                    unsigned short* __restrict__ d0,
                                                    unsigned short* __restrict__ d1,
                                                    unsigned short* __restrict__ d2) {
    const int Q = H_ * D_ / 4;
    int i = blockIdx.x * 256 + threadIdx.x;
    int w = i / Q, j = i - w * Q;
    const float* s = (w == 0) ? s0 : (w == 1) ? s1 : s2;
    unsigned short* d = (w == 0) ? d0 : (w == 1) ? d1 : d2;
    float4 v = *(const float4*)(s + (size_t)j * 4);
    ushort4 o = {bfbits(v.x), bfbits(v.y), bfbits(v.z), bfbits(v.w)};
    *(ushort4*)(d + (size_t)j * 4) = o;
}

// ---------------- gemm1: split-bf16 3-term, 64x128 tile, BK=64, swizzled LDS ----------------
__global__ __launch_bounds__(256) void gemm1_kernel(const short* __restrict__ Ahg,
                                                    const short* __restrict__ Alg,
                                                    const short* __restrict__ Bhg,
                                                    const short* __restrict__ Blg,
                                                    const float* __restrict__ bias,
                                                    float* __restrict__ C,
                                                    unsigned short* __restrict__ hi) {
    __shared__ short lAh[64*64], lAl[64*64], lBh[128*64], lBl[128*64];   // 48 KB
    const int tid = threadIdx.x, lane = tid & 63, wave = tid >> 6;
    const int row0 = blockIdx.y * 64, col0 = blockIdx.x * 128;
    f32x4 acc[4][2] = {};
    for (int kt = 0; kt < D_; kt += 64) {
        #pragma unroll
        for (int q = 0; q < 2; q++) {
            int l = q * 256 + tid;
            int r = l >> 3, cg = ((l & 7) ^ (r & 7)) * 8;
            size_t go = (size_t)(row0 + r) * D_ + kt + cg;
            __builtin_amdgcn_global_load_lds((const AS1 unsigned*)(Ahg + go),
                (AS3 unsigned*)(lAh + l * 8), 16, 0, 0);
            __builtin_amdgcn_global_load_lds((const AS1 unsigned*)(Alg + go),
                (AS3 unsigned*)(lAl + l * 8), 16, 0, 0);
        }
        #pragma unroll
        for (int q = 0; q < 4; q++) {
            int l = q * 256 + tid;
            int r = l >> 3, cg = ((l & 7) ^ (r & 7)) * 8;
            size_t go = (size_t)(col0 + r) * D_ + kt + cg;
            __builtin_amdgcn_global_load_lds((const AS1 unsigned*)(Bhg + go),
                (AS3 unsigned*)(lBh + l * 8), 16, 0, 0);
            __builtin_amdgcn_global_load_lds((const AS1 unsigned*)(Blg + go),
                (AS3 unsigned*)(lBl + l * 8), 16, 0, 0);
        }
        __syncthreads();
        #pragma unroll
        for (int kk = 0; kk < 2; kk++) {
            const int cb = kk * 4 + (lane >> 4);
            short8 ah[4], al[4], bh[2], bl[2];
            #pragma unroll
            for (int i = 0; i < 4; i++) {
                int r = i * 16 + (lane & 15);
                int s = (r * 8 + (cb ^ (r & 7))) * 8;
                ah[i] = *(const short8*)(lAh + s);
                al[i] = *(const short8*)(lAl + s);
            }
            #pragma unroll
            for (int j = 0; j < 2; j++) {
                int r = wave * 32 + j * 16 + (lane & 15);
                int s = (r * 8 + (cb ^ (r & 7))) * 8;
                bh[j] = *(const short8*)(lBh + s);
                bl[j] = *(const short8*)(lBl + s);
            }
            #pragma unroll
            for (int i = 0; i < 4; i++)
                #pragma unroll
                for (int j = 0; j < 2; j++) {
                    acc[i][j] = __builtin_amdgcn_mfma_f32_16x16x32_bf16(al[i], bh[j], acc[i][j], 0, 0, 0);
                    acc[i][j] = __builtin_amdgcn_mfma_f32_16x16x32_bf16(ah[i], bl[j], acc[i][j], 0, 0, 0);
                    acc[i][j] = __builtin_amdgcn_mfma_f32_16x16x32_bf16(ah[i], bh[j], acc[i][j], 0, 0, 0);
                }
        }
        __syncthreads();
    }
    #pragma unroll
    for (int i = 0; i < 4; i++) {
        int row = row0 + i * 16 + (lane >> 4) * 4;
        #pragma unroll
        for (int j = 0; j < 2; j++) {
            int col = col0 + wave * 32 + j * 16 + (lane & 15);
            float bv = bias[col];
            #pragma unroll
            for (int r = 0; r < 4; r++) {
                float v = fmaxf(acc[i][j][r] + bv, 0.0f);
                size_t o = (size_t)(row + r) * H_ + col;
                C[o] = v;
                hi[o] = bfbits(v);
            }
        }
    }
}

// ---------------- gemm2: plain bf16, 64x128 tile, BK=64, swizzled; fused hist8 ----------------
__global__ __launch_bounds__(256) void gemm2_kernel(const short* __restrict__ Ahg,
                                                    const short* __restrict__ Bhg,
                                                    const float* __restrict__ bias,
                                                    float* __restrict__ C,
                                                    unsigned* __restrict__ h8) {
    __shared__ short lAh[64*64], lBh[128*64];   // 24 KB
    __shared__ unsigned lh[256];
    const int tid = threadIdx.x, lane = tid & 63, wave = tid >> 6;
    const int row0 = blockIdx.y * 64, col0 = blockIdx.x * 128;
    lh[tid] = 0;
    f32x4 acc[4][2] = {};
    for (int kt = 0; kt < H_; kt += 64) {
        #pragma unroll
        for (int q = 0; q < 2; q++) {
            int l = q * 256 + tid;
            int r = l >> 3, cg = ((l & 7) ^ (r & 7)) * 8;
            __builtin_amdgcn_global_load_lds(
                (const AS1 unsigned*)(Ahg + (size_t)(row0 + r) * H_ + kt + cg),
                (AS3 unsigned*)(lAh + l * 8), 16, 0, 0);
        }
        #pragma unroll
        for (int q = 0; q < 4; q++) {
            int l = q * 256 + tid;
            int r = l >> 3, cg = ((l & 7) ^ (r & 7)) * 8;
            __builtin_amdgcn_global_load_lds(
                (const AS1 unsigned*)(Bhg + (size_t)(col0 + r) * H_ + kt + cg),
                (AS3 unsigned*)(lBh + l * 8), 16, 0, 0);
        }
        __syncthreads();
        #pragma unroll
        for (int kk = 0; kk < 2; kk++) {
            const int cb = kk * 4 + (lane >> 4);
            short8 ah[4], bh[2];
            #pragma unroll
            for (int i = 0; i < 4; i++) {
                int r = i * 16 + (lane & 15);
                ah[i] = *(const short8*)(lAh + (r * 8 + (cb ^ (r & 7))) * 8);
            }
            #pragma unroll
            for (int j = 0; j < 2; j++) {
                int r = wave * 32 + j * 16 + (lane & 15);
                bh[j] = *(const short8*)(lBh + (r * 8 + (cb ^ (r & 7))) * 8);
            }
            #pragma unroll
            for (int i = 0; i < 4; i++)
                #pragma unroll
                for (int j = 0; j < 2; j++)
                    acc[i][j] = __builtin_amdgcn_mfma_f32_16x16x32_bf16(ah[i], bh[j], acc[i][j], 0, 0, 0);
        }
        __syncthreads();
    }
    const int b = row0 >> 7;
    #pragma unroll
    for (int i = 0; i < 4; i++) {
        int row = row0 + i * 16 + (lane >> 4) * 4;
        #pragma unroll
        for (int j = 0; j < 2; j++) {
            int col = col0 + wave * 32 + j * 16 + (lane & 15);
            float bv = bias[col];
            #pragma unroll
            for (int r = 0; r < 4; r++) {
                float v = acc[i][j][r] + bv;
                C[(size_t)(row + r) * H_ + col] = v;
                atomicAdd(&lh[tokey(v) >> 24], 1u);
            }
        }
    }
    __syncthreads();
    unsigned hv = lh[tid];
    if (hv) atomicAdd(&h8[(b << 8) + tid], hv);
}

// ---------------- fused up-proj: B-rows gathered by sel, bias-select + GELU epilogue --------
__global__ __launch_bounds__(256) void upgemm_kernel(const short* __restrict__ A,
                                                     const short* __restrict__ Wp,
                                                     const short* __restrict__ Wc,
                                                     const float* __restrict__ bp,
                                                     const float* __restrict__ bc,
                                                     const unsigned* __restrict__ sel,
                                                     __hip_bfloat16* __restrict__ act) {
    __shared__ short As[128 * 32];
    __shared__ short Bs[128 * 32];
    const int tid = threadIdx.x, lane = tid & 63, wave = tid >> 6;
    const int wr = wave >> 1, wcol = wave & 1;
    const int b = blockIdx.y;
    const int row0 = b * 128, col0 = blockIdx.x * 128;
    const int r_ld = tid >> 2, c_ld = (tid & 3) * 8;
    const short* B0 = sel[(b << 12) + col0 + r_ld]      ? Wp : Wc;
    const short* B1 = sel[(b << 12) + col0 + 64 + r_ld] ? Wp : Wc;
    f32x4 acc[4][4] = {};
    for (int kt = 0; kt < D_; kt += 32) {
        __builtin_amdgcn_global_load_lds(
            (const AS1 unsigned*)(A + (size_t)(row0 + r_ld) * D_ + kt + c_ld),
            (AS3 unsigned*)(As + r_ld * 32 + c_ld), 16, 0, 0);
        __builtin_amdgcn_global_load_lds(
            (const AS1 unsigned*)(A + (size_t)(row0 + 64 + r_ld) * D_ + kt + c_ld),
            (AS3 unsigned*)(As + (64 + r_ld) * 32 + c_ld), 16, 0, 0);
        __builtin_amdgcn_global_load_lds(
            (const AS1 unsigned*)(B0 + (size_t)(col0 + r_ld) * D_ + kt + c_ld),
            (AS3 unsigned*)(Bs + r_ld * 32 + c_ld), 16, 0, 0);
        __builtin_amdgcn_global_load_lds(
            (const AS1 unsigned*)(B1 + (size_t)(col0 + 64 + r_ld) * D_ + kt + c_ld),
            (AS3 unsigned*)(Bs + (64 + r_ld) * 32 + c_ld), 16, 0, 0);
        __syncthreads();
        short8 af[4], bfr[4];
        #pragma unroll
        for (int t = 0; t < 4; t++) {
            af[t]  = *(const short8*)(As + (wr*64 + t*16 + (lane & 15)) * 32 + (lane >> 4) * 8);
            bfr[t] = *(const short8*)(Bs + (wcol*64 + t*16 + (lane & 15)) * 32 + (lane >> 4) * 8);
        }
        #pragma unroll
        for (int tm = 0; tm < 4; tm++)
            #pragma unroll
            for (int tn = 0; tn < 4; tn++)
                acc[tm][tn] = __builtin_amdgcn_mfma_f32_16x16x32_bf16(af[tm], bfr[tn], acc[tm][tn], 0, 0, 0);
        __syncthreads();
    }
    #pragma unroll
    for (int tm = 0; tm < 4; tm++) {
        int row = row0 + wr*64 + tm*16 + (lane >> 4) * 4;
        #pragma unroll
        for (int tn = 0; tn < 4; tn++) {
            int col = col0 + wcol*64 + tn*16 + (lane & 15);
            float bv = sel[(b << 12) + col] ? bp[col] : bc[col];
            #pragma unroll
            for (int r = 0; r < 4; r++) {
                float v = acc[tm][tn][r] + bv;
                float gl = 0.5f * v * (1.0f + erff(v * 0.70710678118654752440f));
                act[(size_t)(row + r) * H_ + col] = __float2bfloat16(gl);
            }
        }
    }
}

// ---------------- down-proj with split-K=4 into partial buffers ----------------
__global__ __launch_bounds__(256) void bgemm_down_kernel(const short* __restrict__ A,
                                                         const short* __restrict__ Bw,
                                                         float* __restrict__ P) {
    __shared__ short As[128 * 32];
    __shared__ short Bs[128 * 32];
    const int tid = threadIdx.x, lane = tid & 63, wave = tid >> 6;
    const int wr = wave >> 1, wc = wave & 1;
    const int row0 = blockIdx.y * 128, col0 = blockIdx.x * 128;
    const int k0 = blockIdx.z * (H_ / 4);
    float* C = P + (size_t)blockIdx.z * (M_ * D_);
    const int r_ld = tid >> 2, c_ld = (tid & 3) * 8;
    f32x4 acc[4][4] = {};
    for (int kt = k0; kt < k0 + H_ / 4; kt += 32) {
        #pragma unroll
        for (int half = 0; half < 2; half++) {
            int r = half * 64 + r_ld;
            __builtin_amdgcn_global_load_lds(
                (const AS1 unsigned*)(A + (size_t)(row0 + r) * H_ + kt + c_ld),
                (AS3 unsigned*)(As + r * 32 + c_ld), 16, 0, 0);
            __builtin_amdgcn_global_load_lds(
                (const AS1 unsigned*)(Bw + (size_t)(col0 + r) * H_ + kt + c_ld),
                (AS3 unsigned*)(Bs + r * 32 + c_ld), 16, 0, 0);
        }
        __syncthreads();
        short8 af[4], bfr[4];
        #pragma unroll
        for (int t = 0; t < 4; t++) {
            af[t]  = *(const short8*)(As + (wr*64 + t*16 + (lane & 15)) * 32 + (lane >> 4) * 8);
            bfr[t] = *(const short8*)(Bs + (wc*64 + t*16 + (lane & 15)) * 32 + (lane >> 4) * 8);
        }
        #pragma unroll
        for (int tm = 0; tm < 4; tm++)
            #pragma unroll
            for (int tn = 0; tn < 4; tn++)
                acc[tm][tn] = __builtin_amdgcn_mfma_f32_16x16x32_bf16(af[tm], bfr[tn], acc[tm][tn], 0, 0, 0);
        __syncthreads();
    }
    #pragma unroll
    for (int tm = 0; tm < 4; tm++) {
        int row = row0 + wr*64 + tm*16 + (lane >> 4) * 4;
        #pragma unroll
        for (int tn = 0; tn < 4; tn++) {
            int col = col0 + wc*64 + tn*16 + (lane & 15);
            #pragma unroll
            for (int r = 0; r < 4; r++)
                C[(size_t)(row + r) * D_ + col] = acc[tm][tn][r];
        }
    }
}

__global__ __launch_bounds__(256) void down_merge_kernel(const float* __restrict__ P,
                                                         const float* __restrict__ db,
                                                         float* __restrict__ out) {
    int i = blockIdx.x * 256 + threadIdx.x;
    if (i >= M_ * D_ / 4) return;
    int col = (i * 4) & (D_ - 1);
    float4 a = *(const float4*)(P + (size_t)i * 4);
    float4 b = *(const float4*)(P + (size_t)(M_*D_) + (size_t)i * 4);
    float4 c = *(const float4*)(P + (size_t)(2*M_*D_) + (size_t)i * 4);
    float4 d = *(const float4*)(P + (size_t)(3*M_*D_) + (size_t)i * 4);
    float4 o;
    o.x = a.x + b.x + c.x + d.x + db[col+0];
    o.y = a.y + b.y + c.y + d.y + db[col+1];
    o.z = a.z + b.z + c.z + d.z + db[col+2];
    o.w = a.w + b.w + c.w + d.w + db[col+3];
    *(float4*)(out + (size_t)i * 4) = o;
}

// ---------------- threshold scans ----------------
__global__ __launch_bounds__(256) void scan8_kernel(const unsigned* __restrict__ h8,
                                                    unsigned* __restrict__ prefix1,
                                                    unsigned* __restrict__ above1) {
    int b = blockIdx.x, tid = threadIdx.x;
    __shared__ unsigned S[256];
    __shared__ int tstar;
    S[tid] = h8[(b << 8) + tid];
    __syncthreads();
    for (int off = 1; off < 256; off <<= 1) {
        unsigned a = S[tid];
        unsigned v = (tid + off < 256) ? S[tid + off] : 0u;
        __syncthreads();
        S[tid] = a + v;
        __syncthreads();
    }
    unsigned St = S[tid];
    unsigned Sn = (tid < 255) ? S[tid + 1] : 0u;
    if (St >= TOPK_K && (tid == 255 || Sn < TOPK_K)) tstar = tid;
    __syncthreads();
    if (tid == 0) {
        prefix1[b] = (unsigned)tstar;
        above1[b]  = (tstar < 255) ? S[tstar + 1] : 0u;
    }
}

__global__ __launch_bounds__(256) void hist16_kernel(const float* __restrict__ scores,
                                                     const unsigned* __restrict__ prefix1,
                                                     unsigned* __restrict__ h16) {
    int i = blockIdx.x * 256 + threadIdx.x;
    if (i >= NSCORE) return;
    int b = i >> 19;
    unsigned key = tokey(scores[i]);
    if ((key >> 24) == prefix1[b])
        atomicAdd(&h16[((size_t)b << 16) + ((key >> 8) & 0xFFFFu)], 1u);
}

__global__ __launch_bounds__(256) void scan16_kernel(const unsigned* __restrict__ h16,
                                                     const unsigned* __restrict__ prefix1,
                                                     const unsigned* __restrict__ above1,
                                                     float* __restrict__ Thi,
                                                     float* __restrict__ Tlo) {
    int b = blockIdx.x, tid = threadIdx.x;
    const unsigned* h = h16 + ((size_t)b << 16);
    unsigned k = TOPK_K - above1[b];
    __shared__ unsigned S[256];
    __shared__ int tstar;
    unsigned s = 0;
    const unsigned* seg = h + tid * 256;
    for (int i = 0; i < 256; i++) s += seg[i];
    S[tid] = s;
    __syncthreads();
    for (int off = 1; off < 256; off <<= 1) {
        unsigned a = S[tid];
        unsigned v = (tid + off < 256) ? S[tid + off] : 0u;
        __syncthreads();
        S[tid] = a + v;
        __syncthreads();
    }
    unsigned St = S[tid];
    unsigned Sn = (tid < 255) ? S[tid + 1] : 0u;
    if (St >= k && (tid == 255 || Sn < k)) tstar = tid;
    __syncthreads();
    if (tid == 0) {
        int t = tstar;
        unsigned runn = (t < 255) ? S[t + 1] : 0u;
        unsigned c = (unsigned)t * 256u;
        for (int i = 255; i >= 0; i--) {
            unsigned cc = h[t * 256 + i];
            if (runn + cc >= k) { c = (unsigned)(t * 256 + i); break; }
            runn += cc;
        }
        unsigned P24 = (prefix1[b] << 16) | c;
        float tlo = (P24 < 0x8000u) ? -INFINITY : keytofloat(P24 << 8);
        float thi = (P24 == 0x00FFFFFFu) ? INFINITY
                  : ((P24 + 1u) < 0x8000u ? -INFINITY : keytofloat((P24 + 1u) << 8));
        Thi[b] = thi + MARGIN;
        Tlo[b] = tlo - MARGIN;
    }
}

// ---------------- classify: block-owned tiles; LDS-buffered band append ----------------
__global__ __launch_bounds__(256) void classify_kernel(const float* __restrict__ scores,
                                                       const float* __restrict__ Thi,
                                                       const float* __restrict__ Tlo,
                                                       unsigned* __restrict__ sel,
                                                       unsigned* __restrict__ partialCnt,
                                                       unsigned* __restrict__ bandN,
                                                       unsigned* __restrict__ bandIdx) {
    const int b  = blockIdx.z;
    const int h0 = blockIdx.x * 256;
    const int s0 = blockIdx.y * 16;
    const int c  = threadIdx.x;
    const float thi = Thi[b], tlo = Tlo[b];
    __shared__ unsigned lidx[1024];
    __shared__ unsigned lcnt, lbase;
    __shared__ unsigned red[256];
    if (c == 0) lcnt = 0;
    __syncthreads();
    unsigned selbit = 0, cnt = 0;
    const float* base = scores + ((size_t)(b * S_ + s0)) * H_ + h0;
    #pragma unroll 4
    for (int j = 0; j < 16; j++) {
        float sv = base[(size_t)j * H_ + c];
        if (sv > thi) { selbit = 1u; cnt++; }
        else if (sv >= tlo) {
            unsigned slot = atomicAdd(&lcnt, 1u);        // LDS atomic — fast
            if (slot < 1024u) lidx[slot] = (unsigned)(((s0 + j) << 12) | (h0 + c));
        }
    }
    if (selbit) sel[(b << 12) + h0 + c] = 1u;
    red[c] = cnt;
    __syncthreads();
    for (int off = 128; off; off >>= 1) {
        if (c < off) red[c] += red[c + off];
        __syncthreads();
    }
    unsigned nloc = lcnt > 1024u ? 1024u : lcnt;
    if (c == 0) {
        partialCnt[b * 128 + blockIdx.y * 16 + blockIdx.x] = red[0];
        lbase = nloc ? atomicAdd(&bandN[b], nloc) : 0u;  // one global atomic per block
    }
    __syncthreads();
    for (unsigned i = c; i < nloc; i += 256) {
        unsigned p = lbase + i;
        if (p < BAND_CAP) bandIdx[(b << 13) + p] = lidx[i];
    }
}

__global__ void finalize_cnt_kernel(const unsigned* __restrict__ partial,
                                    unsigned* __restrict__ certN) {
    int b = threadIdx.x;
    if (b >= B_) return;
    unsigned s = 0;
    for (int i = 0; i < 128; i++) s += partial[b * 128 + i];
    certN[b] = s;
}

// ---------------- exact fp32 score for band entries ----------------
// Grid 1024 blocks = 4096 waves (~16/CU): entry-per-wave, flat stride. HBM-bound by design.
__global__ __launch_bounds__(256) void band_exact_kernel(const float* __restrict__ g,
                                                         const float* __restrict__ w2,
                                                         const float* __restrict__ b2,
                                                         const unsigned* __restrict__ bandN,
                                                         const unsigned* __restrict__ bandIdx,
                                                         float* __restrict__ bandVal) {
    int wid = (blockIdx.x * 256 + threadIdx.x) >> 6;   // 0..4095
    int lane = threadIdx.x & 63;
    for (int b = 0; b < B_; b++) {
        int n = bandN[b]; if (n > BAND_CAP) n = BAND_CAP;
        for (int j = wid; j < n; j += 4096) {
            unsigned f = bandIdx[(b << 13) + j];
            int m = b * S_ + (int)(f >> 12);
            int h = (int)(f & (H_ - 1));
            const float* gr = g  + (size_t)m * H_;
            const float* wr = w2 + (size_t)h * H_;
            float s = 0.0f;
            for (int cc = lane * 4; cc < H_; cc += 256) {
                float4 a = *(const float4*)(gr + cc);
                float4 w = *(const float4*)(wr + cc);
                s += a.x*w.x + a.y*w.y + a.z*w.z + a.w*w.w;
            }
            #pragma unroll
            for (int off = 32; off; off >>= 1) s += __shfl_xor(s, off);
            if (lane == 0) bandVal[(b << 13) + j] = s + b2[h];
        }
    }
}

// ---------------- band top-r via LDS histogram (O(n)) ----------------
#define NBIN 4096
__global__ __launch_bounds__(256) void band_select_kernel(const float* __restrict__ bandVal,
                                                          const unsigned* __restrict__ bandIdx,
                                                          const unsigned* __restrict__ bandN,
                                                          const unsigned* __restrict__ certN,
                                                          const float* __restrict__ ThiA,
                                                          const float* __restrict__ TloA,
                                                          unsigned* __restrict__ sel) {
    int b = blockIdx.x, tid = threadIdx.x;
    int n = bandN[b]; if (n > BAND_CAP) n = BAND_CAP;
    int r = TOPK_K - (int)certN[b];
    if (r <= 0) return;
    if (r >= n) {
        for (int j = tid; j < n; j += 256)
            sel[(b << 12) + (bandIdx[(b << 13) + j] & (H_ - 1))] = 1u;
        return;
    }
    const float lo = TloA[b];
    const float scale = (float)NBIN / (ThiA[b] - lo);
    __shared__ unsigned hist[NBIN];
    __shared__ unsigned part[256];
    __shared__ unsigned bstar, cabove, mcnt;
    for (int i = tid; i < NBIN; i += 256) hist[i] = 0;
    if (tid == 0) mcnt = 0;
    __syncthreads();
    for (int j = tid; j < n; j += 256) {
        float v = bandVal[(b << 13) + j];
        int bin = (int)((v - lo) * scale);
        bin = bin < 0 ? 0 : (bin >= NBIN ? NBIN - 1 : bin);
        atomicAdd(&hist[bin], 1u);
    }
    __syncthreads();
    unsigned s = 0;
    for (int i = 0; i < 16; i++) s += hist[tid * 16 + i];
    part[tid] = s;
    __syncthreads();
    for (int off = 1; off < 256; off <<= 1) {
        unsigned a = part[tid];
        unsigned v = (tid + off < 256) ? part[tid + off] : 0u;
        __syncthreads();
        part[tid] = a + v;
        __syncthreads();
    }
    unsigned St = part[tid], Sn = (tid < 255) ? part[tid + 1] : 0u;
    if (St >= (unsigned)r && (tid == 255 || Sn < (unsigned)r)) {
        unsigned runn = Sn;
        for (int i = 15; i >= 0; i--) {
            unsigned c = hist[tid * 16 + i];
            if (runn + c >= (unsigned)r) { bstar = (unsigned)(tid * 16 + i); cabove = runn; break; }
            runn += c;
        }
    }
    __syncthreads();
    const int bs = (int)bstar;
    __shared__ float  cv[512];
    __shared__ unsigned ci[512];
    for (int j = tid; j < n; j += 256) {
        float v = bandVal[(b << 13) + j];
        unsigned f = bandIdx[(b << 13) + j];
        int bin = (int)((v - lo) * scale);
        bin = bin < 0 ? 0 : (bin >= NBIN ? NBIN - 1 : bin);
        if (bin > bs) sel[(b << 12) + (f & (H_ - 1))] = 1u;
        else if (bin == bs) {
            unsigned slot = atomicAdd(&mcnt, 1u);
            if (slot < 512u) { cv[slot] = v; ci[slot] = f; }
        }
    }
    __syncthreads();
    int need = r - (int)cabove;
    int mm = mcnt > 512u ? 512 : (int)mcnt;
    for (int j = tid; j < mm; j += 256) {
        float vj = cv[j]; unsigned fj = ci[j];
        int rank = 0;
        for (int l = 0; l < mm; l++) {
            float vl = cv[l]; unsigned fl = ci[l];
            rank += (vl > vj) || (vl == vj && fl < fj);
        }
        if (rank < need) sel[(b << 12) + (fj & (H_ - 1))] = 1u;
    }
}

extern "C" void kernel_launch(void* const* d_in, const int* in_sizes, int n_in,
                              void* d_out, int out_size, void* d_ws, size_t ws_size,
                              hipStream_t stream) {
    const float* x     = (const float*)d_in[0];
    const float* wprev = (const float*)d_in[1];
    const float* bprev = (const float*)d_in[2];
    const float* wcurr = (const float*)d_in[3];
    const float* bcurr = (const float*)d_in[4];
    const float* gw1   = (const float*)d_in[5];
    const float* gb1   = (const float*)d_in[6];
    const float* gw2   = (const float*)d_in[7];
    const float* gb2   = (const float*)d_in[8];
    const float* dw    = (const float*)d_in[9];
    const float* db    = (const float*)d_in[10];
    float* out = (float*)d_out;
    char* ws = (char*)d_ws;

    float* g      = (float*)(ws + G_OFF);
    float* scores = (float*)(ws + SC_OFF);
    float* dpart  = (float*)(ws + GHI_OFF);          // 16MB (GHI+GLO), after ghi dead
    unsigned short* ghi = (unsigned short*)(ws + GHI_OFF);
    unsigned short* xhi = (unsigned short*)(ws + XHI_OFF);
    unsigned short* xlo = (unsigned short*)(ws + XLO_OFF);
    unsigned short* w1h = (unsigned short*)(ws + W1H_OFF);
    unsigned short* w1l = (unsigned short*)(ws + W1L_OFF);
    unsigned short* w2b = (unsigned short*)(ws + W2B_OFF);
    unsigned short* wpb = (unsigned short*)(ws + WPB_OFF);
    unsigned short* wcb = (unsigned short*)(ws + WCB_OFF);
    unsigned short* wdb = (unsigned short*)(ws + WDB_OFF);
    __hip_bfloat16* act = (__hip_bfloat16*)(ws + ACT_OFF);
    unsigned* h8      = (unsigned*)(ws + H8_OFF);
    unsigned* h16     = (unsigned*)(ws + H16_OFF);
    unsigned* sel     = (unsigned*)(ws + SEL_OFF);
    unsigned* certN   = (unsigned*)(ws + CNT_OFF);
    unsigned* bandN   = (unsigned*)(ws + CNT_OFF + 32);
    unsigned* prefix1 = (unsigned*)(ws + CNT_OFF + 64);
    unsigned* above1  = (unsigned*)(ws + CNT_OFF + 96);
    float*    Thi     = (float*)(ws + CNT_OFF + 128);
    float*    Tlo     = (float*)(ws + CNT_OFF + 160);
    unsigned* partCnt = (unsigned*)(ws + PART_OFF);
    unsigned* bandIdx = (unsigned*)(ws + BIDX_OFF);
    float*    bandVal = (float*)(ws + BVAL_OFF);

    hipMemsetAsync(ws + H8_OFF, 0, 65536 + 2097152, stream);      // h8 + pad + h16
    hipMemsetAsync(ws + SEL_OFF, 0, 131072 + 512 + 4096, stream); // sel + counters + partCnt

    // gate path
    split_kernel<<<(M_*D_/4 + 255)/256, 256, 0, stream>>>(x,   xhi, xlo, M_*D_/4);
    split_kernel<<<(H_*D_/4 + 255)/256, 256, 0, stream>>>(gw1, w1h, w1l, H_*D_/4);
    gemm1_kernel<<<dim3(H_/128, M_/64), 256, 0, stream>>>(
        (const short*)xhi, (const short*)xlo, (const short*)w1h, (const short*)w1l,
        gb1, g, ghi);
    f2bf_kernel<<<(H_*H_/4 + 255)/256, 256, 0, stream>>>(gw2, w2b, H_*H_/4);   // overwrites w1
    gemm2_kernel<<<dim3(H_/128, M_/64), 256, 0, stream>>>(
        (const short*)ghi, (const short*)w2b, gb2, scores, h8);

    // value-path bf16 weights (overwrite w2b region -> after gemm2)
    f2bf3_kernel<<<3*(H_*D_/4)/256, 256, 0, stream>>>(wprev, wcurr, dw, wpb, wcb, wdb);

    // threshold + classify + band refine
    scan8_kernel<<<B_, 256, 0, stream>>>(h8, prefix1, above1);
    hist16_kernel<<<NSCORE/256, 256, 0, stream>>>(scores, prefix1, h16);
    scan16_kernel<<<B_, 256, 0, stream>>>(h16, prefix1, above1, Thi, Tlo);
    classify_kernel<<<dim3(16, 8, 8), 256, 0, stream>>>(scores, Thi, Tlo, sel, partCnt, bandN, bandIdx);
    finalize_cnt_kernel<<<1, 64, 0, stream>>>(partCnt, certN);
    band_exact_kernel<<<1024, 256, 0, stream>>>(g, gw2, gb2, bandN, bandIdx, bandVal);
    band_select_kernel<<<B_, 256, 0, stream>>>(bandVal, bandIdx, bandN, certN, Thi, Tlo, sel);

    // value path: fused up-proj (sel-gathered weights + bias + GELU), down-proj, merge
    upgemm_kernel<<<dim3(H_/128, B_), 256, 0, stream>>>(
        (const short*)xhi, (const short*)wpb, (const short*)wcb, bprev, bcurr, sel, act);
    bgemm_down_kernel<<<dim3(D_/128, M_/128, 4), 256, 0, stream>>>(
        (const short*)act, (const short*)wdb, dpart);
    down_merge_kernel<<<(M_*D_/4 + 255)/256, 256, 0, stream>>>(dpart, db, out);
}